// Round 3
// baseline (303.274 us; speedup 1.0000x reference)
//
#include <hip/hip_runtime.h>
#include <hip/hip_bf16.h>

// Problem constants
#define Bc 2
#define Nc 6
#define Cc 128
#define Hc 16
#define Wc 44
#define Dc 64
#define HWc (Hc*Wc)          // 704
#define BNc (Bc*Nc)          // 12
#define NRAY (Nc*HWc)        // 4224
#define NPTS (Bc*Nc*Dc*HWc)  // 540672
#define BEV_W 256
#define BEV_H 256
#define BEV_HW (BEV_W*BEV_H) // 65536
#define NSEG (Bc*BEV_HW)     // 131072
#define NSCANB 512           // scan blocks (256 segs each)
#define NGRP (NSEG/16)       // 8192 16-cell output groups
#define GGB 1024             // persistent gather blocks (4 waves each)

// ---------------- workspace layout (bytes) ----------------
#define OFF_KI    0                      // fallback only
#define OFF_DB    512                    // fallback only
#define OFF_CNT   1024                   // int cnt[NSEG]      524288
#define OFF_OFFS  (OFF_CNT  + 524288)    // int offs[NSEG]     524288 (global excl after scanT)
#define OFF_FILL  (OFF_OFFS + 524288)    // (unused in fast path)
#define OFF_BSUM  (OFF_FILL + 524288)    // int bsum[512]
#define OFF_ETOT  (OFF_BSUM + 2048)      // int Etot
#define OFF_WCTR  (OFF_ETOT + 4)         // int work counter (gather queue)
#define OFF_E8    (OFF_BSUM + 4096)      // int2 e8[NPTS]      4325376 {ray|seg<<13, w}
#define OFF_FT    (OFF_E8   + 4325376)   // float ft[B][NRAY][128] 4325376
#define WS_NEED   (OFF_FT   + 4325376)
#define OFF_ACC   (OFF_FT   + 4325376)   // uint pk[NPTS] (rank<<17|seg) 2162688
#define WS_BIG    (OFF_ACC  + 67108864)
#define OFF_FIDX  OFF_E8
#define OFF_FCNT  OFF_CNT

// ---------------------------------------------------------------------------
// numpy-f32-exact setup of Kinv (per bn) and dbins.
// ---------------------------------------------------------------------------
__device__ __forceinline__ void setup_into(int tid, const float* __restrict__ intr,
                                           const int* __restrict__ p_imgh,
                                           const int* __restrict__ p_imgw,
                                           float* Ki, float* db) {
    if (tid < Dc) {
        double v = 1.0 + (double)tid * (59.0 / 63.0);
        db[tid] = (tid == Dc - 1) ? 60.0f : (float)v;
    }
    if (tid >= BNc) return;
    double img_h = (double)p_imgh[0];
    double img_w = (double)p_imgw[0];
    double scale_x = (double)Wc / (img_w / 16.0);
    double scale_y = (double)Hc / (img_h / 16.0);
    float rs0 = (float)(16.0 / scale_x);
    float rs1 = (float)(16.0 / scale_y);
    float rs2 = 1.0f;
    const float* K = intr + tid * 9;
    float k0 = __fmul_rn(K[0], rs0), k1 = __fmul_rn(K[1], rs0), k2 = __fmul_rn(K[2], rs0);
    float k3 = __fmul_rn(K[3], rs1), k4 = __fmul_rn(K[4], rs1), k5 = __fmul_rn(K[5], rs1);
    float k6 = __fmul_rn(K[6], rs2), k7 = __fmul_rn(K[7], rs2), k8 = __fmul_rn(K[8], rs2);
    float c0 = __fsub_rn(__fmul_rn(k4,k8), __fmul_rn(k5,k7));
    float c1 = __fsub_rn(__fmul_rn(k3,k8), __fmul_rn(k5,k6));
    float c2 = __fsub_rn(__fmul_rn(k3,k7), __fmul_rn(k4,k6));
    float det = __fadd_rn(__fsub_rn(__fmul_rn(k0,c0), __fmul_rn(k1,c1)), __fmul_rn(k2,c2));
    float* o = Ki + tid * 9;
    o[0] = __fdiv_rn(c0, det);
    o[1] = __fdiv_rn(__fsub_rn(__fmul_rn(k2,k7), __fmul_rn(k1,k8)), det);
    o[2] = __fdiv_rn(__fsub_rn(__fmul_rn(k1,k5), __fmul_rn(k2,k4)), det);
    o[3] = __fdiv_rn(__fsub_rn(__fmul_rn(k5,k6), __fmul_rn(k3,k8)), det);
    o[4] = __fdiv_rn(__fsub_rn(__fmul_rn(k0,k8), __fmul_rn(k2,k6)), det);
    o[5] = __fdiv_rn(__fsub_rn(__fmul_rn(k2,k3), __fmul_rn(k0,k5)), det);
    o[6] = __fdiv_rn(c2, det);
    o[7] = __fdiv_rn(__fsub_rn(__fmul_rn(k1,k6), __fmul_rn(k0,k7)), det);
    o[8] = __fdiv_rn(__fsub_rn(__fmul_rn(k0,k4), __fmul_rn(k1,k3)), det);
}

__global__ void k_setup(const float* __restrict__ intr, const float* __restrict__ extr,
                        const int* __restrict__ p_imgh, const int* __restrict__ p_imgw,
                        float* __restrict__ Ki, float* __restrict__ db) {
    setup_into(threadIdx.x, intr, p_imgh, p_imgw, Ki, db);
}

// ---------------------------------------------------------------------------
// numpy-f32-exact classify: point gid -> BEV cell (or -1)
// ---------------------------------------------------------------------------
__device__ __forceinline__ int classify_point(int gid, const float* Ki_all,
                                              const float* db, const float* extr) {
    int p   = gid % HWc;
    int tmp = gid / HWc;
    int d   = tmp % Dc;
    int bn  = tmp / Dc;
    int w = p % Wc, h = p / Wc;
    float dd = db[d];
    float ud = __fmul_rn((float)w, dd);
    float vd = __fmul_rn((float)h, dd);
    const float* Ki = Ki_all + bn * 9;
    float pcx = fmaf(Ki[2], dd, fmaf(Ki[1], vd, __fmul_rn(Ki[0], ud)));
    float pcy = fmaf(Ki[5], dd, fmaf(Ki[4], vd, __fmul_rn(Ki[3], ud)));
    float pcz = fmaf(Ki[8], dd, fmaf(Ki[7], vd, __fmul_rn(Ki[6], ud)));
    const float* E = extr + bn * 16;
    float px = __fadd_rn(fmaf(E[2],  pcz, fmaf(E[1], pcy, __fmul_rn(E[0], pcx))), E[3]);
    float py = __fadd_rn(fmaf(E[6],  pcz, fmaf(E[5], pcy, __fmul_rn(E[4], pcx))), E[7]);
    float pz = __fadd_rn(fmaf(E[10], pcz, fmaf(E[9], pcy, __fmul_rn(E[8], pcx))), E[11]);
    float fx = __fdiv_rn(__fsub_rn(px, -51.2f), 0.4f);
    float fy = __fdiv_rn(__fsub_rn(py, -51.2f), 0.4f);
    int xi = (int)fx;
    int yi = (int)fy;
    bool valid = (xi >= 0) && (xi < BEV_W) && (yi >= 0) && (yi < BEV_H)
              && (pz >= -5.0f) && (pz <= 3.0f);
    return valid ? (yi * BEV_W + xi) : -1;
}

// ---------------------------------------------------------------------------
// bsum scan helper — used ONLY by k_scanT.
// ---------------------------------------------------------------------------
__device__ __forceinline__ void scan_bsum(int tid, const int* __restrict__ bsum,
                                          int* sB, int* su, int* pEtotS) {
    int2 v2 = ((const int2*)bsum)[tid];
    int s = v2.x + v2.y;
    su[tid] = s;
    __syncthreads();
    for (int st = 1; st < 256; st <<= 1) {
        int t2 = (tid >= st) ? su[tid - st] : 0;
        __syncthreads();
        su[tid] += t2;
        __syncthreads();
    }
    int base = su[tid] - s;
    sB[2 * tid]     = base;
    sB[2 * tid + 1] = base + v2.x;
    if (tid == 255) *pEtotS = base + s;
    __syncthreads();
}

__device__ __forceinline__ unsigned long long lanemask_le(int lane) {
    return (lane == 63) ? ~0ull : ((1ull << (lane + 1)) - 1ull);
}

// ---------------------------------------------------------------------------
// Kernel A: count (+ fused setup, + fused transpose in first 528 blocks).
// Rank trick: the wave-aggregated atomic's RETURN value gives each point its
// rank within its cell; pack (rank<<17 | seg) into pk.
// ---------------------------------------------------------------------------
__global__ __launch_bounds__(256) void k_count(const float* __restrict__ intr,
                                               const float* __restrict__ extr,
                                               const int* __restrict__ p_imgh,
                                               const int* __restrict__ p_imgw,
                                               const float* __restrict__ feat,
                                               int* __restrict__ cntArr,
                                               unsigned* __restrict__ pk,
                                               float* __restrict__ ft) {
    __shared__ float sKi[BNc * 9];
    __shared__ float sDb[Dc];
    __shared__ float buf[Cc * 17];
    int tid = threadIdx.x;
    setup_into(tid, intr, p_imgh, p_imgw, sKi, sDb);
    __syncthreads();
    int gid = blockIdx.x * 256 + tid;      // grid = NPTS/256 exactly
    int cell = classify_point(gid, sKi, sDb, extr);
    {
        int lane = tid & 63;
        int b = gid / (Nc * Dc * HWc);
        int seg = b * BEV_HW + cell;
        int key = (cell >= 0) ? seg : -1;
        int pkey = __shfl_up(key, 1);
        bool bnd = (lane == 0) || (key != pkey);
        unsigned long long bm = __ballot(bnd);
        int base = 0;
        if (key >= 0 && bnd) {
            unsigned long long rest = (lane == 63) ? 0ull : (bm >> (lane + 1));
            int runlen = (rest != 0ull) ? __ffsll((long long)rest) : (64 - lane);
            base = atomicAdd(&cntArr[seg], runlen);           // returns run's base rank
        }
        int headLane = 63 - __clzll(bm & lanemask_le(lane));
        int rbase = __shfl(base, headLane);
        pk[gid] = (key >= 0)
                ? ((unsigned)seg | ((unsigned)(rbase + (lane - headLane)) << 17))
                : 0xFFFFFFFFu;
    }
    if (blockIdx.x < BNc * (HWc / 16)) {
        int bn   = blockIdx.x / (HWc / 16);
        int tile = blockIdx.x % (HWc / 16);
        const float* fb = feat + (size_t)bn * Cc * HWc + tile * 16;
        for (int i = tid; i < Cc * 16; i += 256) {
            int c = i >> 4, hw = i & 15;
            buf[c * 17 + hw] = fb[c * HWc + hw];
        }
        __syncthreads();
        float* obt = ft + ((size_t)bn * HWc + tile * 16) * Cc;
        for (int i = tid; i < 16 * Cc; i += 256) {
            int r = i >> 7, ch = i & 127;
            obt[(size_t)r * Cc + ch] = buf[ch * 17 + r];
        }
    }
}

// ---------------------------------------------------------------------------
// Kernel B1: block-local exclusive scan (512 x 256).
// ---------------------------------------------------------------------------
__global__ __launch_bounds__(256) void k_scanB(const int* __restrict__ cntArr,
                                               int* __restrict__ offs,
                                               int* __restrict__ bsum) {
    __shared__ int su[256];
    int tid = threadIdx.x;
    int g = blockIdx.x * 256 + tid;
    int v = cntArr[g];
    su[tid] = v;
    __syncthreads();
    for (int st = 1; st < 256; st <<= 1) {
        int t2 = (tid >= st) ? su[tid - st] : 0;
        __syncthreads();
        su[tid] += t2;
        __syncthreads();
    }
    offs[g] = su[tid] - v;
    if (tid == 255) bsum[blockIdx.x] = su[255];
}

// ---------------------------------------------------------------------------
// Kernel B2: globalize — offs[g] += prefix(bsum); publish Etot; reset queue.
// ---------------------------------------------------------------------------
__global__ __launch_bounds__(256) void k_scanT(int* __restrict__ offs,
                                               const int* __restrict__ bsum,
                                               int* __restrict__ EtotG,
                                               int* __restrict__ wctr) {
    __shared__ int sB[NSCANB];
    __shared__ int su[256];
    __shared__ int sE;
    int tid = threadIdx.x;
    scan_bsum(tid, bsum, sB, su, &sE);
    int add = sB[blockIdx.x];
    int g = blockIdx.x * 256 + tid;
    offs[g] += add;
    if (blockIdx.x == 0 && tid == 0) { *EtotG = sE; *wctr = 0; }
}

// ---------------------------------------------------------------------------
// Kernel C: placement — pure streaming (no classify, no atomics, no scan).
// ---------------------------------------------------------------------------
__global__ __launch_bounds__(256) void k_fill(const unsigned* __restrict__ pk,
                                              const float* __restrict__ depth,
                                              const int* __restrict__ offs,
                                              int2* __restrict__ e8) {
    int gid = blockIdx.x * 256 + threadIdx.x;
    unsigned v = pk[gid];
    if (v == 0xFFFFFFFFu) return;
    int seg  = (int)(v & (unsigned)(NSEG - 1));   // 17 bits
    int rank = (int)(v >> 17);
    int pos  = offs[seg] + rank;
    int p  = gid % HWc;
    int bn = gid / (Dc * HWc);
    int ray = (bn % Nc) * HWc + p;
    e8[pos] = make_int2(ray | (seg << 13), __float_as_int(depth[gid]));
}

// per-entry step: accumulate; on (wave-uniform) cell change close the cell
// into the LDS window. TINY body so the u-loops fully unroll and the
// prefetch values stay in registers (round-2 lesson: fat bodies -> scratch).
#define G_STEP(EE, FF) do {                                                     \
    int sg_ = (EE).x >> 13;                                                     \
    if (sg_ != curc) {                                                          \
        if (curc >= 0) *(float2*)&winw[(curc & 15) * 132 + 2 * lane] = a;       \
        curc = sg_; a.x = 0.f; a.y = 0.f;                                       \
    }                                                                           \
    float ww_ = __int_as_float((EE).y);                                         \
    a.x = fmaf(ww_, (FF).x, a.x);                                               \
    a.y = fmaf(ww_, (FF).y, a.y);                                               \
} while (0)

// ---------------------------------------------------------------------------
// Kernel D: group-per-wave gather+finish. Persistent waves grab 16-cell
// output groups from an atomic queue. Entry range = [offs[seg0],
// offs[seg0+16]) — complete cells by construction; no straddler logic,
// no in-loop flush, no zero-role. Group id is readfirstlane-uniform so the
// e8 reads are scalar loads. One flush per group, all writes float4/64B
// (empty cells selected to 0 from the upfront cnt ballot).
// ---------------------------------------------------------------------------
__global__ __launch_bounds__(256) void k_gatherG(const float2* __restrict__ ft2,
                                                 const int2* __restrict__ e8,
                                                 const int* __restrict__ cntArr,
                                                 const int* __restrict__ offs,
                                                 const int* __restrict__ EtotG,
                                                 int* __restrict__ wctr,
                                                 float* __restrict__ out) {
    __shared__ float win[4][16 * 132];
    int tid  = threadIdx.x;
    int w    = tid >> 6, lane = tid & 63;
    float* winw = win[w];
    int Etot = *EtotG;
    int q  = lane & 3;           // flush: quad of 4 cells
    int c0 = lane >> 2;          // flush: channel = c0 + 16*it
    int g0 = q << 2;

    for (;;) {
        int g16t = 0;
        if (lane == 0) g16t = atomicAdd(wctr, 1);
        int g16 = __builtin_amdgcn_readfirstlane(g16t);
        if (g16 >= NGRP) return;

        int seg0 = g16 << 4;
        int cntv = cntArr[seg0 + (lane & 15)];
        unsigned em = (unsigned)__ballot(cntv > 0) & 0xFFFFu;

        int b     = g16 >> 12;
        int cell0 = (g16 & 4095) << 4;
        float* ob = out + (size_t)b * Cc * BEV_HW + cell0;

        if (em == 0u) {                       // whole group empty (periphery)
            float4 z = make_float4(0.f, 0.f, 0.f, 0.f);
            #pragma unroll
            for (int it = 0; it < 8; it++)
                *(float4*)(ob + (size_t)(it * 16 + c0) * BEV_HW + g0) = z;
            continue;
        }

        int k0 = offs[seg0];
        int k1 = (g16 == NGRP - 1) ? Etot : offs[seg0 + 16];
        int total = k1 - k0;

        float2 a = make_float2(0.f, 0.f);
        int curc = -1;
        int j = 0;
        for (; j + 4 <= total; j += 4) {
            int2 ea = e8[k0 + j];
            int2 eb = e8[k0 + j + 1];
            int2 ec = e8[k0 + j + 2];
            int2 ed = e8[k0 + j + 3];
            float2 fa = ft2[((size_t)((ea.x >> 29) * NRAY) + (ea.x & 8191)) * 64 + lane];
            float2 fb = ft2[((size_t)((eb.x >> 29) * NRAY) + (eb.x & 8191)) * 64 + lane];
            float2 fc = ft2[((size_t)((ec.x >> 29) * NRAY) + (ec.x & 8191)) * 64 + lane];
            float2 fd = ft2[((size_t)((ed.x >> 29) * NRAY) + (ed.x & 8191)) * 64 + lane];
            G_STEP(ea, fa); G_STEP(eb, fb); G_STEP(ec, fc); G_STEP(ed, fd);
        }
        for (; j < total; j++) {
            int2 ee = e8[k0 + j];
            float2 f = ft2[((size_t)((ee.x >> 29) * NRAY) + (ee.x & 8191)) * 64 + lane];
            G_STEP(ee, f);
        }
        if (curc >= 0) *(float2*)&winw[(curc & 15) * 132 + 2 * lane] = a;

        // counts for my 4 flush cells (lanes 0..15 hold cnt of cells 0..15)
        float n0 = (float)__shfl(cntv, g0);
        float n1 = (float)__shfl(cntv, g0 + 1);
        float n2 = (float)__shfl(cntv, g0 + 2);
        float n3 = (float)__shfl(cntv, g0 + 3);
        float i0 = __fdiv_rn(1.0f, __fadd_rn(n0, 1e-5f));
        float i1 = __fdiv_rn(1.0f, __fadd_rn(n1, 1e-5f));
        float i2 = __fdiv_rn(1.0f, __fadd_rn(n2, 1e-5f));
        float i3 = __fdiv_rn(1.0f, __fadd_rn(n3, 1e-5f));
        bool o0 = (em >> (g0 + 0)) & 1u;
        bool o1 = (em >> (g0 + 1)) & 1u;
        bool o2 = (em >> (g0 + 2)) & 1u;
        bool o3 = (em >> (g0 + 3)) & 1u;
        #pragma unroll
        for (int it = 0; it < 8; it++) {
            int c = it * 16 + c0;
            float4 v;
            v.x = o0 ? __fmul_rn(winw[(g0 + 0) * 132 + c], i0) : 0.f;
            v.y = o1 ? __fmul_rn(winw[(g0 + 1) * 132 + c], i1) : 0.f;
            v.z = o2 ? __fmul_rn(winw[(g0 + 2) * 132 + c], i2) : 0.f;
            v.w = o3 ? __fmul_rn(winw[(g0 + 3) * 132 + c], i3) : 0.f;
            *(float4*)(ob + (size_t)c * BEV_HW + g0) = v;
        }
    }
}

// ======================= fallback (round-2 proven) ==========================
__global__ __launch_bounds__(256) void k_classifyF(const float* __restrict__ Ki_all,
                                                   const float* __restrict__ db,
                                                   const float* __restrict__ extr,
                                                   int* __restrict__ idxT,
                                                   float* __restrict__ cnt) {
    int gid = blockIdx.x * 256 + threadIdx.x;
    if (gid >= NPTS) return;
    int cell = classify_point(gid, Ki_all, db, extr);
    idxT[gid] = cell;
    if (cell >= 0) {
        int b = gid / (Nc * Dc * HWc);
        atomicAdd(&cnt[b * BEV_HW + cell], 1.0f);
    }
}

__global__ __launch_bounds__(256) void k_scatterF(const float* __restrict__ feat,
                                                  const float* __restrict__ depth,
                                                  const int* __restrict__ idxT,
                                                  float* __restrict__ out) {
    __shared__ float s_dw[HWc];
    __shared__ int   s_idx[HWc];
    int blk = blockIdx.x;
    int bn  = blk / Dc;
    int b   = bn / Nc;
    int tid = threadIdx.x;
    const float* dp = depth + (size_t)blk * HWc;
    const int*   ip = idxT  + (size_t)blk * HWc;
    for (int p = tid; p < HWc; p += 256) { s_dw[p] = dp[p]; s_idx[p] = ip[p]; }
    __syncthreads();
    const float* fb = feat + (size_t)bn * Cc * HWc;
    float*       ob = out  + (size_t)b  * Cc * BEV_HW;
    for (int c = 0; c < Cc; c++) {
        const float* f = fb + (size_t)c * HWc;
        float*       o = ob + (size_t)c * BEV_HW;
        for (int p = tid; p < HWc; p += 256) {
            int cell = s_idx[p];
            if (cell >= 0) atomicAdd(&o[cell], __fmul_rn(f[p], s_dw[p]));
        }
    }
}

__global__ __launch_bounds__(256) void k_normF(float* __restrict__ out,
                                               const float* __restrict__ cnt) {
    int i = blockIdx.x * 256 + threadIdx.x;
    const int total = Bc * Cc * BEV_HW / 4;
    if (i >= total) return;
    int q = i % (BEV_HW / 4);
    int b = i / (Cc * BEV_HW / 4);
    float4 v = ((float4*)out)[i];
    float4 cv = ((const float4*)cnt)[b * (BEV_HW / 4) + q];
    v.x = __fdiv_rn(v.x, __fadd_rn(cv.x, 1e-5f));
    v.y = __fdiv_rn(v.y, __fadd_rn(cv.y, 1e-5f));
    v.z = __fdiv_rn(v.z, __fadd_rn(cv.z, 1e-5f));
    v.w = __fdiv_rn(v.w, __fadd_rn(cv.w, 1e-5f));
    ((float4*)out)[i] = v;
}

// ===========================================================================
extern "C" void kernel_launch(void* const* d_in, const int* in_sizes, int n_in,
                              void* d_out, int out_size, void* d_ws, size_t ws_size,
                              hipStream_t stream) {
    const float* feat  = (const float*)d_in[0];
    const float* depth = (const float*)d_in[1];
    const float* intr  = (const float*)d_in[2];
    const float* extr  = (const float*)d_in[3];
    const int*   imh   = (const int*)d_in[4];
    const int*   imw   = (const int*)d_in[5];
    float* out = (float*)d_out;
    char*  ws  = (char*)d_ws;

    if (ws_size >= (size_t)WS_BIG) {
        int*      cntA  = (int*)(ws + OFF_CNT);
        int*      offs  = (int*)(ws + OFF_OFFS);
        int*      bsum  = (int*)(ws + OFF_BSUM);
        int*      EtotG = (int*)(ws + OFF_ETOT);
        int*      wctr  = (int*)(ws + OFF_WCTR);
        int2*     e8    = (int2*)(ws + OFF_E8);
        float*    ft    = (float*)(ws + OFF_FT);
        unsigned* pk    = (unsigned*)(ws + OFF_ACC);

        hipMemsetAsync(cntA, 0, (size_t)NSEG * sizeof(int), stream);
        k_count<<<NPTS / 256, 256, 0, stream>>>(intr, extr, imh, imw, feat, cntA, pk, ft);
        k_scanB<<<NSCANB, 256, 0, stream>>>(cntA, offs, bsum);
        k_scanT<<<NSCANB, 256, 0, stream>>>(offs, bsum, EtotG, wctr);
        k_fill<<<NPTS / 256, 256, 0, stream>>>(pk, depth, offs, e8);
        k_gatherG<<<GGB, 256, 0, stream>>>((const float2*)ft, e8, cntA, offs, EtotG, wctr, out);
    } else {
        float* Ki   = (float*)(ws + OFF_KI);
        float* db   = (float*)(ws + OFF_DB);
        int*   idxT = (int*)(ws + OFF_FIDX);
        float* cnt  = (float*)(ws + OFF_FCNT);
        hipMemsetAsync(out, 0, (size_t)out_size * sizeof(float), stream);
        hipMemsetAsync(cnt, 0, (size_t)Bc * BEV_HW * sizeof(float), stream);
        k_setup<<<1, 64, 0, stream>>>(intr, extr, imh, imw, Ki, db);
        k_classifyF<<<(NPTS + 255) / 256, 256, 0, stream>>>(Ki, db, extr, idxT, cnt);
        k_scatterF<<<Bc * Nc * Dc, 256, 0, stream>>>(feat, depth, idxT, out);
        k_normF<<<(Bc * Cc * BEV_HW / 4 + 255) / 256, 256, 0, stream>>>(out, cnt);
    }
}

// Round 4
// 172.157 us; speedup vs baseline: 1.7616x; 1.7616x over previous
//
#include <hip/hip_runtime.h>
#include <hip/hip_bf16.h>

// Problem constants
#define Bc 2
#define Nc 6
#define Cc 128
#define Hc 16
#define Wc 44
#define Dc 64
#define HWc (Hc*Wc)          // 704
#define BNc (Bc*Nc)          // 12
#define NRAY (Nc*HWc)        // 4224
#define NPTS (Bc*Nc*Dc*HWc)  // 540672
#define BEV_W 256
#define BEV_H 256
#define BEV_HW (BEV_W*BEV_H) // 65536
#define NSEG (Bc*BEV_HW)     // 131072
#define NSCANB 512           // scan blocks (256 segs each)
#define NGRP (NSEG/16)       // 8192 16-cell output groups
#define GB  768              // gather-role blocks (4 waves each)
#define GW  (GB*4)           // 3072 gather waves
#define ZB  256              // zero-role blocks
#define ZW  (ZB*4)           // 1024 zero waves

// ---------------- workspace layout (bytes) ----------------
#define OFF_KI    0                      // fallback only
#define OFF_DB    512                    // fallback only
#define OFF_CNT   1024                   // int cnt[NSEG]      524288
#define OFF_OFFS  (OFF_CNT  + 524288)    // int offs[NSEG]     524288 (global excl after scanT)
#define OFF_FILL  (OFF_OFFS + 524288)    // (unused in fast path)
#define OFF_BSUM  (OFF_FILL + 524288)    // int bsum[512]
#define OFF_ETOT  (OFF_BSUM + 2048)      // int Etot
#define OFF_E8    (OFF_BSUM + 4096)      // int2 e8[NPTS]      4325376 {ray|seg<<13, w}
#define OFF_FT    (OFF_E8   + 4325376)   // float ft[B][NRAY][128] 4325376
#define WS_NEED   (OFF_FT   + 4325376)
#define OFF_ACC   (OFF_FT   + 4325376)   // uint pk[NPTS] (rank<<17|seg) 2162688
#define WS_BIG    (OFF_ACC  + 67108864)
#define OFF_FIDX  OFF_E8
#define OFF_FCNT  OFF_CNT

// ---------------------------------------------------------------------------
// numpy-f32-exact setup of Kinv (per bn) and dbins.
// ---------------------------------------------------------------------------
__device__ __forceinline__ void setup_into(int tid, const float* __restrict__ intr,
                                           const int* __restrict__ p_imgh,
                                           const int* __restrict__ p_imgw,
                                           float* Ki, float* db) {
    if (tid < Dc) {
        double v = 1.0 + (double)tid * (59.0 / 63.0);
        db[tid] = (tid == Dc - 1) ? 60.0f : (float)v;
    }
    if (tid >= BNc) return;
    double img_h = (double)p_imgh[0];
    double img_w = (double)p_imgw[0];
    double scale_x = (double)Wc / (img_w / 16.0);
    double scale_y = (double)Hc / (img_h / 16.0);
    float rs0 = (float)(16.0 / scale_x);
    float rs1 = (float)(16.0 / scale_y);
    float rs2 = 1.0f;
    const float* K = intr + tid * 9;
    float k0 = __fmul_rn(K[0], rs0), k1 = __fmul_rn(K[1], rs0), k2 = __fmul_rn(K[2], rs0);
    float k3 = __fmul_rn(K[3], rs1), k4 = __fmul_rn(K[4], rs1), k5 = __fmul_rn(K[5], rs1);
    float k6 = __fmul_rn(K[6], rs2), k7 = __fmul_rn(K[7], rs2), k8 = __fmul_rn(K[8], rs2);
    float c0 = __fsub_rn(__fmul_rn(k4,k8), __fmul_rn(k5,k7));
    float c1 = __fsub_rn(__fmul_rn(k3,k8), __fmul_rn(k5,k6));
    float c2 = __fsub_rn(__fmul_rn(k3,k7), __fmul_rn(k4,k6));
    float det = __fadd_rn(__fsub_rn(__fmul_rn(k0,c0), __fmul_rn(k1,c1)), __fmul_rn(k2,c2));
    float* o = Ki + tid * 9;
    o[0] = __fdiv_rn(c0, det);
    o[1] = __fdiv_rn(__fsub_rn(__fmul_rn(k2,k7), __fmul_rn(k1,k8)), det);
    o[2] = __fdiv_rn(__fsub_rn(__fmul_rn(k1,k5), __fmul_rn(k2,k4)), det);
    o[3] = __fdiv_rn(__fsub_rn(__fmul_rn(k5,k6), __fmul_rn(k3,k8)), det);
    o[4] = __fdiv_rn(__fsub_rn(__fmul_rn(k0,k8), __fmul_rn(k2,k6)), det);
    o[5] = __fdiv_rn(__fsub_rn(__fmul_rn(k2,k3), __fmul_rn(k0,k5)), det);
    o[6] = __fdiv_rn(c2, det);
    o[7] = __fdiv_rn(__fsub_rn(__fmul_rn(k1,k6), __fmul_rn(k0,k7)), det);
    o[8] = __fdiv_rn(__fsub_rn(__fmul_rn(k0,k4), __fmul_rn(k1,k3)), det);
}

__global__ void k_setup(const float* __restrict__ intr, const float* __restrict__ extr,
                        const int* __restrict__ p_imgh, const int* __restrict__ p_imgw,
                        float* __restrict__ Ki, float* __restrict__ db) {
    setup_into(threadIdx.x, intr, p_imgh, p_imgw, Ki, db);
}

// ---------------------------------------------------------------------------
// numpy-f32-exact classify: point gid -> BEV cell (or -1)
// ---------------------------------------------------------------------------
__device__ __forceinline__ int classify_point(int gid, const float* Ki_all,
                                              const float* db, const float* extr) {
    int p   = gid % HWc;
    int tmp = gid / HWc;
    int d   = tmp % Dc;
    int bn  = tmp / Dc;
    int w = p % Wc, h = p / Wc;
    float dd = db[d];
    float ud = __fmul_rn((float)w, dd);
    float vd = __fmul_rn((float)h, dd);
    const float* Ki = Ki_all + bn * 9;
    float pcx = fmaf(Ki[2], dd, fmaf(Ki[1], vd, __fmul_rn(Ki[0], ud)));
    float pcy = fmaf(Ki[5], dd, fmaf(Ki[4], vd, __fmul_rn(Ki[3], ud)));
    float pcz = fmaf(Ki[8], dd, fmaf(Ki[7], vd, __fmul_rn(Ki[6], ud)));
    const float* E = extr + bn * 16;
    float px = __fadd_rn(fmaf(E[2],  pcz, fmaf(E[1], pcy, __fmul_rn(E[0], pcx))), E[3]);
    float py = __fadd_rn(fmaf(E[6],  pcz, fmaf(E[5], pcy, __fmul_rn(E[4], pcx))), E[7]);
    float pz = __fadd_rn(fmaf(E[10], pcz, fmaf(E[9], pcy, __fmul_rn(E[8], pcx))), E[11]);
    float fx = __fdiv_rn(__fsub_rn(px, -51.2f), 0.4f);
    float fy = __fdiv_rn(__fsub_rn(py, -51.2f), 0.4f);
    int xi = (int)fx;
    int yi = (int)fy;
    bool valid = (xi >= 0) && (xi < BEV_W) && (yi >= 0) && (yi < BEV_H)
              && (pz >= -5.0f) && (pz <= 3.0f);
    return valid ? (yi * BEV_W + xi) : -1;
}

// ---------------------------------------------------------------------------
// bsum scan helper — used ONLY by k_scanT.
// ---------------------------------------------------------------------------
__device__ __forceinline__ void scan_bsum(int tid, const int* __restrict__ bsum,
                                          int* sB, int* su, int* pEtotS) {
    int2 v2 = ((const int2*)bsum)[tid];
    int s = v2.x + v2.y;
    su[tid] = s;
    __syncthreads();
    for (int st = 1; st < 256; st <<= 1) {
        int t2 = (tid >= st) ? su[tid - st] : 0;
        __syncthreads();
        su[tid] += t2;
        __syncthreads();
    }
    int base = su[tid] - s;
    sB[2 * tid]     = base;
    sB[2 * tid + 1] = base + v2.x;
    if (tid == 255) *pEtotS = base + s;
    __syncthreads();
}

__device__ __forceinline__ unsigned long long lanemask_le(int lane) {
    return (lane == 63) ? ~0ull : ((1ull << (lane + 1)) - 1ull);
}

// ---------------------------------------------------------------------------
// Kernel A: count (+ fused setup, + fused transpose in first 528 blocks).
// Rank trick: the wave-aggregated atomic's RETURN value gives each point its
// rank within its cell; pack (rank<<17 | seg) into pk.
// ---------------------------------------------------------------------------
__global__ __launch_bounds__(256) void k_count(const float* __restrict__ intr,
                                               const float* __restrict__ extr,
                                               const int* __restrict__ p_imgh,
                                               const int* __restrict__ p_imgw,
                                               const float* __restrict__ feat,
                                               int* __restrict__ cntArr,
                                               unsigned* __restrict__ pk,
                                               float* __restrict__ ft) {
    __shared__ float sKi[BNc * 9];
    __shared__ float sDb[Dc];
    __shared__ float buf[Cc * 17];
    int tid = threadIdx.x;
    setup_into(tid, intr, p_imgh, p_imgw, sKi, sDb);
    __syncthreads();
    int gid = blockIdx.x * 256 + tid;      // grid = NPTS/256 exactly
    int cell = classify_point(gid, sKi, sDb, extr);
    {
        int lane = tid & 63;
        int b = gid / (Nc * Dc * HWc);
        int seg = b * BEV_HW + cell;
        int key = (cell >= 0) ? seg : -1;
        int pkey = __shfl_up(key, 1);
        bool bnd = (lane == 0) || (key != pkey);
        unsigned long long bm = __ballot(bnd);
        int base = 0;
        if (key >= 0 && bnd) {
            unsigned long long rest = (lane == 63) ? 0ull : (bm >> (lane + 1));
            int runlen = (rest != 0ull) ? __ffsll((long long)rest) : (64 - lane);
            base = atomicAdd(&cntArr[seg], runlen);           // returns run's base rank
        }
        int headLane = 63 - __clzll(bm & lanemask_le(lane));
        int rbase = __shfl(base, headLane);
        pk[gid] = (key >= 0)
                ? ((unsigned)seg | ((unsigned)(rbase + (lane - headLane)) << 17))
                : 0xFFFFFFFFu;
    }
    if (blockIdx.x < BNc * (HWc / 16)) {
        int bn   = blockIdx.x / (HWc / 16);
        int tile = blockIdx.x % (HWc / 16);
        const float* fb = feat + (size_t)bn * Cc * HWc + tile * 16;
        for (int i = tid; i < Cc * 16; i += 256) {
            int c = i >> 4, hw = i & 15;
            buf[c * 17 + hw] = fb[c * HWc + hw];
        }
        __syncthreads();
        float* obt = ft + ((size_t)bn * HWc + tile * 16) * Cc;
        for (int i = tid; i < 16 * Cc; i += 256) {
            int r = i >> 7, ch = i & 127;
            obt[(size_t)r * Cc + ch] = buf[ch * 17 + r];
        }
    }
}

// ---------------------------------------------------------------------------
// Kernel B1: block-local exclusive scan (512 x 256).
// ---------------------------------------------------------------------------
__global__ __launch_bounds__(256) void k_scanB(const int* __restrict__ cntArr,
                                               int* __restrict__ offs,
                                               int* __restrict__ bsum) {
    __shared__ int su[256];
    int tid = threadIdx.x;
    int g = blockIdx.x * 256 + tid;
    int v = cntArr[g];
    su[tid] = v;
    __syncthreads();
    for (int st = 1; st < 256; st <<= 1) {
        int t2 = (tid >= st) ? su[tid - st] : 0;
        __syncthreads();
        su[tid] += t2;
        __syncthreads();
    }
    offs[g] = su[tid] - v;
    if (tid == 255) bsum[blockIdx.x] = su[255];
}

// ---------------------------------------------------------------------------
// Kernel B2: globalize — offs[g] += prefix(bsum); publish Etot.
// ---------------------------------------------------------------------------
__global__ __launch_bounds__(256) void k_scanT(int* __restrict__ offs,
                                               const int* __restrict__ bsum,
                                               int* __restrict__ EtotG) {
    __shared__ int sB[NSCANB];
    __shared__ int su[256];
    __shared__ int sE;
    int tid = threadIdx.x;
    scan_bsum(tid, bsum, sB, su, &sE);
    int add = sB[blockIdx.x];
    int g = blockIdx.x * 256 + tid;
    offs[g] += add;
    if (blockIdx.x == 0 && tid == 0) *EtotG = sE;
}

// ---------------------------------------------------------------------------
// Kernel C: placement — pure streaming (no classify, no atomics, no scan).
// ---------------------------------------------------------------------------
__global__ __launch_bounds__(256) void k_fill(const unsigned* __restrict__ pk,
                                              const float* __restrict__ depth,
                                              const int* __restrict__ offs,
                                              int2* __restrict__ e8) {
    int gid = blockIdx.x * 256 + threadIdx.x;
    unsigned v = pk[gid];
    if (v == 0xFFFFFFFFu) return;
    int seg  = (int)(v & (unsigned)(NSEG - 1));   // 17 bits
    int rank = (int)(v >> 17);
    int pos  = offs[seg] + rank;
    int p  = gid % HWc;
    int bn = gid / (Dc * HWc);
    int ray = (bn % Nc) * HWc + p;
    e8[pos] = make_int2(ray | (seg << 13), __float_as_int(depth[gid]));
}

// per-entry step. Cell close writes the cell's 128 channels straight from
// registers (lane holds channels 2*lane, 2*lane+1), normalization folded in
// (wave owns the whole cell so segN == cnt). ~12 instrs, branch wave-uniform
// and rarely taken -> no codegen bloat, no LDS window, no flush.
#define G_STEP(EE, FF) do {                                                     \
    int sg_ = (EE).x >> 13;                                                     \
    if (sg_ != curc) {                                                          \
        if (curc >= 0) {                                                        \
            float inv_ = __fdiv_rn(1.0f, __fadd_rn((float)segN, 1e-5f));        \
            size_t ba_ = ((size_t)((curc >> 16) * Cc + 2 * lane)) * BEV_HW      \
                         + (curc & 65535);                                      \
            out[ba_]          = __fmul_rn(a.x, inv_);                           \
            out[ba_ + BEV_HW] = __fmul_rn(a.y, inv_);                           \
        }                                                                       \
        curc = sg_; a.x = 0.f; a.y = 0.f; segN = 0;                             \
    }                                                                           \
    segN++;                                                                     \
    float ww_ = __int_as_float((EE).y);                                         \
    a.x = fmaf(ww_, (FF).x, a.x);                                               \
    a.y = fmaf(ww_, (FF).y, a.y);                                               \
} while (0)

#define FIDX(EE) (((size_t)(((EE).x >> 29) * NRAY) + ((EE).x & 8191)) * 64 + lane)

// ---------------------------------------------------------------------------
// Kernel D: static entry-range gather (round-1 proven ownership: each wave
// processes every cell whose run STARTS in its range, extended through the
// end straddler; waves starting mid-cell skip it). No queue (round-3 lesson:
// one global atomic counter cross-XCD serialized the whole kernel). Blocks
// >= GB are zero-role: write zeros for empty cells (disjoint writes).
// ---------------------------------------------------------------------------
__global__ __launch_bounds__(256) void k_gatherS(const float2* __restrict__ ft2,
                                                 const int2* __restrict__ e8,
                                                 const int* __restrict__ cntArr,
                                                 const int* __restrict__ offs,
                                                 const int* __restrict__ EtotG,
                                                 float* __restrict__ out) {
    int tid  = threadIdx.x;
    int w    = tid >> 6, lane = tid & 63;

    if (blockIdx.x >= GB) {
        // ---- zero-role: fill empty cells of out ----
        int zwid = (blockIdx.x - GB) * 4 + w;
        int q = lane & 3, c0 = lane >> 2;      // all-empty path
        int g = lane & 15, cq = lane >> 4;     // partial path
        for (int g16 = zwid; g16 < NGRP; g16 += ZW) {
            int n = (lane < 16) ? cntArr[(g16 << 4) + lane] : 1;
            unsigned long long bz = __ballot(n == 0);
            unsigned em = (unsigned)bz & 0xFFFFu;
            if (em == 0) continue;
            int b = g16 >> 12;
            int cell0 = (g16 & 4095) << 4;
            float* ob = out + (size_t)b * Cc * BEV_HW + cell0;
            if (em == 0xFFFFu) {               // whole group empty (periphery)
                float4 z = make_float4(0.f, 0.f, 0.f, 0.f);
                #pragma unroll
                for (int it = 0; it < 8; it++)
                    *(float4*)(ob + (size_t)(it * 16 + c0) * BEV_HW + (q << 2)) = z;
            } else {
                bool own = (em >> g) & 1u;
                #pragma unroll 4
                for (int c4 = 0; c4 < Cc; c4 += 4) {
                    if (own) ob[(size_t)(c4 + cq) * BEV_HW + g] = 0.f;
                }
            }
        }
        return;
    }

    // ---- gather-role: static entry range ----
    int Etot = *EtotG;
    int wid  = blockIdx.x * 4 + w;
    int WCH  = (Etot + GW - 1) / GW;
    if (WCH <= 0) return;
    int start = wid * WCH;
    if (start >= Etot) return;
    int end = start + WCH; if (end > Etot) end = Etot;
    int k0 = 0;
    if (start > 0) {
        int segP = e8[start - 1].x >> 13;
        k0 = offs[segP] + cntArr[segP];          // end of segP's run
        if (k0 >= end) return;                   // no cell starts here
    }
    int segE = e8[end - 1].x >> 13;
    int kend = offs[segE] + cntArr[segE];        // extend thru straddler
    int total = kend - k0;

    float2 a = make_float2(0.f, 0.f);
    int curc = -1;
    int segN = 0;
    int j = 0;

    int2 e0, e1, e2, e3;
    if (total >= 4) { e0 = e8[k0]; e1 = e8[k0+1]; e2 = e8[k0+2]; e3 = e8[k0+3]; }
    for (; j + 8 <= total; j += 4) {
        float2 f0 = ft2[FIDX(e0)];
        float2 f1 = ft2[FIDX(e1)];
        float2 f2 = ft2[FIDX(e2)];
        float2 f3 = ft2[FIDX(e3)];
        int2 n0 = e8[k0 + j + 4];
        int2 n1 = e8[k0 + j + 5];
        int2 n2 = e8[k0 + j + 6];
        int2 n3 = e8[k0 + j + 7];
        G_STEP(e0, f0); G_STEP(e1, f1); G_STEP(e2, f2); G_STEP(e3, f3);
        e0 = n0; e1 = n1; e2 = n2; e3 = n3;
    }
    if (total >= 4) {                            // drain the loaded batch
        float2 f0 = ft2[FIDX(e0)];
        float2 f1 = ft2[FIDX(e1)];
        float2 f2 = ft2[FIDX(e2)];
        float2 f3 = ft2[FIDX(e3)];
        G_STEP(e0, f0); G_STEP(e1, f1); G_STEP(e2, f2); G_STEP(e3, f3);
        j += 4;
    }
    for (; j < total; j++) {
        int2 ee = e8[k0 + j];
        float2 f = ft2[FIDX(ee)];
        G_STEP(ee, f);
    }
    if (curc >= 0) {                             // close final cell
        float inv_ = __fdiv_rn(1.0f, __fadd_rn((float)segN, 1e-5f));
        size_t ba_ = ((size_t)((curc >> 16) * Cc + 2 * lane)) * BEV_HW + (curc & 65535);
        out[ba_]          = __fmul_rn(a.x, inv_);
        out[ba_ + BEV_HW] = __fmul_rn(a.y, inv_);
    }
}

// ======================= fallback (round-2 proven) ==========================
__global__ __launch_bounds__(256) void k_classifyF(const float* __restrict__ Ki_all,
                                                   const float* __restrict__ db,
                                                   const float* __restrict__ extr,
                                                   int* __restrict__ idxT,
                                                   float* __restrict__ cnt) {
    int gid = blockIdx.x * 256 + threadIdx.x;
    if (gid >= NPTS) return;
    int cell = classify_point(gid, Ki_all, db, extr);
    idxT[gid] = cell;
    if (cell >= 0) {
        int b = gid / (Nc * Dc * HWc);
        atomicAdd(&cnt[b * BEV_HW + cell], 1.0f);
    }
}

__global__ __launch_bounds__(256) void k_scatterF(const float* __restrict__ feat,
                                                  const float* __restrict__ depth,
                                                  const int* __restrict__ idxT,
                                                  float* __restrict__ out) {
    __shared__ float s_dw[HWc];
    __shared__ int   s_idx[HWc];
    int blk = blockIdx.x;
    int bn  = blk / Dc;
    int b   = bn / Nc;
    int tid = threadIdx.x;
    const float* dp = depth + (size_t)blk * HWc;
    const int*   ip = idxT  + (size_t)blk * HWc;
    for (int p = tid; p < HWc; p += 256) { s_dw[p] = dp[p]; s_idx[p] = ip[p]; }
    __syncthreads();
    const float* fb = feat + (size_t)bn * Cc * HWc;
    float*       ob = out  + (size_t)b  * Cc * BEV_HW;
    for (int c = 0; c < Cc; c++) {
        const float* f = fb + (size_t)c * HWc;
        float*       o = ob + (size_t)c * BEV_HW;
        for (int p = tid; p < HWc; p += 256) {
            int cell = s_idx[p];
            if (cell >= 0) atomicAdd(&o[cell], __fmul_rn(f[p], s_dw[p]));
        }
    }
}

__global__ __launch_bounds__(256) void k_normF(float* __restrict__ out,
                                               const float* __restrict__ cnt) {
    int i = blockIdx.x * 256 + threadIdx.x;
    const int total = Bc * Cc * BEV_HW / 4;
    if (i >= total) return;
    int q = i % (BEV_HW / 4);
    int b = i / (Cc * BEV_HW / 4);
    float4 v = ((float4*)out)[i];
    float4 cv = ((const float4*)cnt)[b * (BEV_HW / 4) + q];
    v.x = __fdiv_rn(v.x, __fadd_rn(cv.x, 1e-5f));
    v.y = __fdiv_rn(v.y, __fadd_rn(cv.y, 1e-5f));
    v.z = __fdiv_rn(v.z, __fadd_rn(cv.z, 1e-5f));
    v.w = __fdiv_rn(v.w, __fadd_rn(cv.w, 1e-5f));
    ((float4*)out)[i] = v;
}

// ===========================================================================
extern "C" void kernel_launch(void* const* d_in, const int* in_sizes, int n_in,
                              void* d_out, int out_size, void* d_ws, size_t ws_size,
                              hipStream_t stream) {
    const float* feat  = (const float*)d_in[0];
    const float* depth = (const float*)d_in[1];
    const float* intr  = (const float*)d_in[2];
    const float* extr  = (const float*)d_in[3];
    const int*   imh   = (const int*)d_in[4];
    const int*   imw   = (const int*)d_in[5];
    float* out = (float*)d_out;
    char*  ws  = (char*)d_ws;

    if (ws_size >= (size_t)WS_BIG) {
        int*      cntA  = (int*)(ws + OFF_CNT);
        int*      offs  = (int*)(ws + OFF_OFFS);
        int*      bsum  = (int*)(ws + OFF_BSUM);
        int*      EtotG = (int*)(ws + OFF_ETOT);
        int2*     e8    = (int2*)(ws + OFF_E8);
        float*    ft    = (float*)(ws + OFF_FT);
        unsigned* pk    = (unsigned*)(ws + OFF_ACC);

        hipMemsetAsync(cntA, 0, (size_t)NSEG * sizeof(int), stream);
        k_count<<<NPTS / 256, 256, 0, stream>>>(intr, extr, imh, imw, feat, cntA, pk, ft);
        k_scanB<<<NSCANB, 256, 0, stream>>>(cntA, offs, bsum);
        k_scanT<<<NSCANB, 256, 0, stream>>>(offs, bsum, EtotG);
        k_fill<<<NPTS / 256, 256, 0, stream>>>(pk, depth, offs, e8);
        k_gatherS<<<GB + ZB, 256, 0, stream>>>((const float2*)ft, e8, cntA, offs, EtotG, out);
    } else {
        float* Ki   = (float*)(ws + OFF_KI);
        float* db   = (float*)(ws + OFF_DB);
        int*   idxT = (int*)(ws + OFF_FIDX);
        float* cnt  = (float*)(ws + OFF_FCNT);
        hipMemsetAsync(out, 0, (size_t)out_size * sizeof(float), stream);
        hipMemsetAsync(cnt, 0, (size_t)Bc * BEV_HW * sizeof(float), stream);
        k_setup<<<1, 64, 0, stream>>>(intr, extr, imh, imw, Ki, db);
        k_classifyF<<<(NPTS + 255) / 256, 256, 0, stream>>>(Ki, db, extr, idxT, cnt);
        k_scatterF<<<Bc * Nc * Dc, 256, 0, stream>>>(feat, depth, idxT, out);
        k_normF<<<(Bc * Cc * BEV_HW / 4 + 255) / 256, 256, 0, stream>>>(out, cnt);
    }
}

// Round 5
// 148.937 us; speedup vs baseline: 2.0363x; 1.1559x over previous
//
#include <hip/hip_runtime.h>
#include <hip/hip_bf16.h>

// Problem constants
#define Bc 2
#define Nc 6
#define Cc 128
#define Hc 16
#define Wc 44
#define Dc 64
#define HWc (Hc*Wc)          // 704
#define BNc (Bc*Nc)          // 12
#define NRAY (Nc*HWc)        // 4224
#define NPTS (Bc*Nc*Dc*HWc)  // 540672
#define BEV_W 256
#define BEV_H 256
#define BEV_HW (BEV_W*BEV_H) // 65536
#define NSEG (Bc*BEV_HW)     // 131072
#define NSCANB 512           // scan blocks (256 segs each)
#define NGRP (NSEG/16)       // 8192 16-cell output groups
#define GB  768              // gather-role blocks (4 waves each)
#define GW  (GB*4)           // 3072 gather waves
#define ZB  256              // zero-role blocks
#define ZW  (ZB*4)           // 1024 zero waves

// ---------------- workspace layout (bytes) ----------------
#define OFF_KI    0                      // fallback only
#define OFF_DB    512                    // fallback only
#define OFF_CNT   1024                   // int cnt[NSEG]      524288
#define OFF_OFFS  (OFF_CNT  + 524288)    // int offs[NSEG]     524288 (global excl after scanT)
#define OFF_FILL  (OFF_OFFS + 524288)    // (unused in fast path)
#define OFF_BSUM  (OFF_FILL + 524288)    // int bsum[512]
#define OFF_ETOT  (OFF_BSUM + 2048)      // int Etot
#define OFF_E8    (OFF_BSUM + 4096)      // int2 e8[NPTS]      4325376 {ray|seg<<13, w}
#define OFF_FT    (OFF_E8   + 4325376)   // float ft[B][NRAY][128] 4325376
#define WS_NEED   (OFF_FT   + 4325376)
#define OFF_ACC   (OFF_FT   + 4325376)   // uint pk[NPTS] (rank<<17|seg) 2162688
#define WS_BIG    (OFF_ACC  + 67108864)
#define OFF_FIDX  OFF_E8
#define OFF_FCNT  OFF_CNT

// ---------------------------------------------------------------------------
// numpy-f32-exact setup of Kinv (per bn) and dbins.
// ---------------------------------------------------------------------------
__device__ __forceinline__ void setup_into(int tid, const float* __restrict__ intr,
                                           const int* __restrict__ p_imgh,
                                           const int* __restrict__ p_imgw,
                                           float* Ki, float* db) {
    if (tid < Dc) {
        double v = 1.0 + (double)tid * (59.0 / 63.0);
        db[tid] = (tid == Dc - 1) ? 60.0f : (float)v;
    }
    if (tid >= BNc) return;
    double img_h = (double)p_imgh[0];
    double img_w = (double)p_imgw[0];
    double scale_x = (double)Wc / (img_w / 16.0);
    double scale_y = (double)Hc / (img_h / 16.0);
    float rs0 = (float)(16.0 / scale_x);
    float rs1 = (float)(16.0 / scale_y);
    float rs2 = 1.0f;
    const float* K = intr + tid * 9;
    float k0 = __fmul_rn(K[0], rs0), k1 = __fmul_rn(K[1], rs0), k2 = __fmul_rn(K[2], rs0);
    float k3 = __fmul_rn(K[3], rs1), k4 = __fmul_rn(K[4], rs1), k5 = __fmul_rn(K[5], rs1);
    float k6 = __fmul_rn(K[6], rs2), k7 = __fmul_rn(K[7], rs2), k8 = __fmul_rn(K[8], rs2);
    float c0 = __fsub_rn(__fmul_rn(k4,k8), __fmul_rn(k5,k7));
    float c1 = __fsub_rn(__fmul_rn(k3,k8), __fmul_rn(k5,k6));
    float c2 = __fsub_rn(__fmul_rn(k3,k7), __fmul_rn(k4,k6));
    float det = __fadd_rn(__fsub_rn(__fmul_rn(k0,c0), __fmul_rn(k1,c1)), __fmul_rn(k2,c2));
    float* o = Ki + tid * 9;
    o[0] = __fdiv_rn(c0, det);
    o[1] = __fdiv_rn(__fsub_rn(__fmul_rn(k2,k7), __fmul_rn(k1,k8)), det);
    o[2] = __fdiv_rn(__fsub_rn(__fmul_rn(k1,k5), __fmul_rn(k2,k4)), det);
    o[3] = __fdiv_rn(__fsub_rn(__fmul_rn(k5,k6), __fmul_rn(k3,k8)), det);
    o[4] = __fdiv_rn(__fsub_rn(__fmul_rn(k0,k8), __fmul_rn(k2,k6)), det);
    o[5] = __fdiv_rn(__fsub_rn(__fmul_rn(k2,k3), __fmul_rn(k0,k5)), det);
    o[6] = __fdiv_rn(c2, det);
    o[7] = __fdiv_rn(__fsub_rn(__fmul_rn(k1,k6), __fmul_rn(k0,k7)), det);
    o[8] = __fdiv_rn(__fsub_rn(__fmul_rn(k0,k4), __fmul_rn(k1,k3)), det);
}

__global__ void k_setup(const float* __restrict__ intr, const float* __restrict__ extr,
                        const int* __restrict__ p_imgh, const int* __restrict__ p_imgw,
                        float* __restrict__ Ki, float* __restrict__ db) {
    setup_into(threadIdx.x, intr, p_imgh, p_imgw, Ki, db);
}

// ---------------------------------------------------------------------------
// numpy-f32-exact classify: point gid -> BEV cell (or -1)
// ---------------------------------------------------------------------------
__device__ __forceinline__ int classify_point(int gid, const float* Ki_all,
                                              const float* db, const float* extr) {
    int p   = gid % HWc;
    int tmp = gid / HWc;
    int d   = tmp % Dc;
    int bn  = tmp / Dc;
    int w = p % Wc, h = p / Wc;
    float dd = db[d];
    float ud = __fmul_rn((float)w, dd);
    float vd = __fmul_rn((float)h, dd);
    const float* Ki = Ki_all + bn * 9;
    float pcx = fmaf(Ki[2], dd, fmaf(Ki[1], vd, __fmul_rn(Ki[0], ud)));
    float pcy = fmaf(Ki[5], dd, fmaf(Ki[4], vd, __fmul_rn(Ki[3], ud)));
    float pcz = fmaf(Ki[8], dd, fmaf(Ki[7], vd, __fmul_rn(Ki[6], ud)));
    const float* E = extr + bn * 16;
    float px = __fadd_rn(fmaf(E[2],  pcz, fmaf(E[1], pcy, __fmul_rn(E[0], pcx))), E[3]);
    float py = __fadd_rn(fmaf(E[6],  pcz, fmaf(E[5], pcy, __fmul_rn(E[4], pcx))), E[7]);
    float pz = __fadd_rn(fmaf(E[10], pcz, fmaf(E[9], pcy, __fmul_rn(E[8], pcx))), E[11]);
    float fx = __fdiv_rn(__fsub_rn(px, -51.2f), 0.4f);
    float fy = __fdiv_rn(__fsub_rn(py, -51.2f), 0.4f);
    int xi = (int)fx;
    int yi = (int)fy;
    bool valid = (xi >= 0) && (xi < BEV_W) && (yi >= 0) && (yi < BEV_H)
              && (pz >= -5.0f) && (pz <= 3.0f);
    return valid ? (yi * BEV_W + xi) : -1;
}

// ---------------------------------------------------------------------------
// bsum scan helper — used ONLY by k_scanT.
// ---------------------------------------------------------------------------
__device__ __forceinline__ void scan_bsum(int tid, const int* __restrict__ bsum,
                                          int* sB, int* su, int* pEtotS) {
    int2 v2 = ((const int2*)bsum)[tid];
    int s = v2.x + v2.y;
    su[tid] = s;
    __syncthreads();
    for (int st = 1; st < 256; st <<= 1) {
        int t2 = (tid >= st) ? su[tid - st] : 0;
        __syncthreads();
        su[tid] += t2;
        __syncthreads();
    }
    int base = su[tid] - s;
    sB[2 * tid]     = base;
    sB[2 * tid + 1] = base + v2.x;
    if (tid == 255) *pEtotS = base + s;
    __syncthreads();
}

__device__ __forceinline__ unsigned long long lanemask_le(int lane) {
    return (lane == 63) ? ~0ull : ((1ull << (lane + 1)) - 1ull);
}

// ---------------------------------------------------------------------------
// Kernel A: count (+ fused setup, + fused transpose in first 528 blocks).
// Rank trick: the wave-aggregated atomic's RETURN value gives each point its
// rank within its cell; pack (rank<<17 | seg) into pk.
// ---------------------------------------------------------------------------
__global__ __launch_bounds__(256) void k_count(const float* __restrict__ intr,
                                               const float* __restrict__ extr,
                                               const int* __restrict__ p_imgh,
                                               const int* __restrict__ p_imgw,
                                               const float* __restrict__ feat,
                                               int* __restrict__ cntArr,
                                               unsigned* __restrict__ pk,
                                               float* __restrict__ ft) {
    __shared__ float sKi[BNc * 9];
    __shared__ float sDb[Dc];
    __shared__ float buf[Cc * 17];
    int tid = threadIdx.x;
    setup_into(tid, intr, p_imgh, p_imgw, sKi, sDb);
    __syncthreads();
    int gid = blockIdx.x * 256 + tid;      // grid = NPTS/256 exactly
    int cell = classify_point(gid, sKi, sDb, extr);
    {
        int lane = tid & 63;
        int b = gid / (Nc * Dc * HWc);
        int seg = b * BEV_HW + cell;
        int key = (cell >= 0) ? seg : -1;
        int pkey = __shfl_up(key, 1);
        bool bnd = (lane == 0) || (key != pkey);
        unsigned long long bm = __ballot(bnd);
        int base = 0;
        if (key >= 0 && bnd) {
            unsigned long long rest = (lane == 63) ? 0ull : (bm >> (lane + 1));
            int runlen = (rest != 0ull) ? __ffsll((long long)rest) : (64 - lane);
            base = atomicAdd(&cntArr[seg], runlen);           // returns run's base rank
        }
        int headLane = 63 - __clzll(bm & lanemask_le(lane));
        int rbase = __shfl(base, headLane);
        pk[gid] = (key >= 0)
                ? ((unsigned)seg | ((unsigned)(rbase + (lane - headLane)) << 17))
                : 0xFFFFFFFFu;
    }
    if (blockIdx.x < BNc * (HWc / 16)) {
        int bn   = blockIdx.x / (HWc / 16);
        int tile = blockIdx.x % (HWc / 16);
        const float* fb = feat + (size_t)bn * Cc * HWc + tile * 16;
        for (int i = tid; i < Cc * 16; i += 256) {
            int c = i >> 4, hw = i & 15;
            buf[c * 17 + hw] = fb[c * HWc + hw];
        }
        __syncthreads();
        float* obt = ft + ((size_t)bn * HWc + tile * 16) * Cc;
        for (int i = tid; i < 16 * Cc; i += 256) {
            int r = i >> 7, ch = i & 127;
            obt[(size_t)r * Cc + ch] = buf[ch * 17 + r];
        }
    }
}

// ---------------------------------------------------------------------------
// Kernel B1: block-local exclusive scan (512 x 256).
// ---------------------------------------------------------------------------
__global__ __launch_bounds__(256) void k_scanB(const int* __restrict__ cntArr,
                                               int* __restrict__ offs,
                                               int* __restrict__ bsum) {
    __shared__ int su[256];
    int tid = threadIdx.x;
    int g = blockIdx.x * 256 + tid;
    int v = cntArr[g];
    su[tid] = v;
    __syncthreads();
    for (int st = 1; st < 256; st <<= 1) {
        int t2 = (tid >= st) ? su[tid - st] : 0;
        __syncthreads();
        su[tid] += t2;
        __syncthreads();
    }
    offs[g] = su[tid] - v;
    if (tid == 255) bsum[blockIdx.x] = su[255];
}

// ---------------------------------------------------------------------------
// Kernel B2: globalize — offs[g] += prefix(bsum); publish Etot.
// ---------------------------------------------------------------------------
__global__ __launch_bounds__(256) void k_scanT(int* __restrict__ offs,
                                               const int* __restrict__ bsum,
                                               int* __restrict__ EtotG) {
    __shared__ int sB[NSCANB];
    __shared__ int su[256];
    __shared__ int sE;
    int tid = threadIdx.x;
    scan_bsum(tid, bsum, sB, su, &sE);
    int add = sB[blockIdx.x];
    int g = blockIdx.x * 256 + tid;
    offs[g] += add;
    if (blockIdx.x == 0 && tid == 0) *EtotG = sE;
}

// ---------------------------------------------------------------------------
// Kernel C: placement — pure streaming (no classify, no atomics, no scan).
// ---------------------------------------------------------------------------
__global__ __launch_bounds__(256) void k_fill(const unsigned* __restrict__ pk,
                                              const float* __restrict__ depth,
                                              const int* __restrict__ offs,
                                              int2* __restrict__ e8) {
    int gid = blockIdx.x * 256 + threadIdx.x;
    unsigned v = pk[gid];
    if (v == 0xFFFFFFFFu) return;
    int seg  = (int)(v & (unsigned)(NSEG - 1));   // 17 bits
    int rank = (int)(v >> 17);
    int pos  = offs[seg] + rank;
    int p  = gid % HWc;
    int bn = gid / (Dc * HWc);
    int ray = (bn % Nc) * HWc + p;
    e8[pos] = make_int2(ray | (seg << 13), __float_as_int(depth[gid]));
}

// per-entry step: accumulate; on (wave-uniform) cell change close the cell
// into the LDS window (tiny: float2 ds_write + mask or). No flush here —
// entries of one outer-loop iteration all belong to ONE group.
#define G_STEP(EE, FF) do {                                                     \
    int sg_ = (EE).x >> 13;                                                     \
    if (sg_ != curc) {                                                          \
        if (curc >= 0) {                                                        \
            *(float2*)&winw[(curc & 15) * 132 + 2 * lane] = a;                  \
            mask |= 1u << (curc & 15);                                          \
        }                                                                       \
        curc = sg_; a.x = 0.f; a.y = 0.f;                                       \
    }                                                                           \
    float ww_ = __int_as_float((EE).y);                                         \
    a.x = fmaf(ww_, (FF).x, a.x);                                               \
    a.y = fmaf(ww_, (FF).y, a.y);                                               \
} while (0)

#define FIDX(EE) (((size_t)(((EE).x >> 29) * NRAY) + ((EE).x & 8191)) * 64 + lane)

// ---------------------------------------------------------------------------
// Kernel D: static entry-range gather + per-group LDS window flush.
// Combines round-4's balanced spill-free partition (ownership by run-start,
// extended through the end straddler) with round-3's full-line window flush
// (WRITE_SIZE was exactly ideal there). Outer loop per touched group: group
// end known from global offs[(g16+1)*16] — no scanning. Flush at ONE site
// (round-1/2 codegen failures structurally excluded). Interior groups
// (mask|empty == 0xFFFF) take the full-64B-line float4 path; masked path
// only for the <=2 boundary groups per wave. Empty cells of touched groups
// are zeroed by the flusher (duplicate zeros between sharing waves benign).
// Blocks >= GB zero only entry-free groups (full-line zeros).
// ---------------------------------------------------------------------------
__global__ __launch_bounds__(256) void k_gatherW(const float2* __restrict__ ft2,
                                                 const int2* __restrict__ e8,
                                                 const int* __restrict__ cntArr,
                                                 const int* __restrict__ offs,
                                                 const int* __restrict__ EtotG,
                                                 float* __restrict__ out) {
    __shared__ float win[4][16 * 132];
    int tid  = threadIdx.x;
    int w    = tid >> 6, lane = tid & 63;
    int Etot = *EtotG;

    if (blockIdx.x >= GB) {
        // ---- zero-role: groups with NO entries (BEV periphery) ----
        int zwid = (blockIdx.x - GB) * 4 + w;
        int q = lane & 3, c0 = lane >> 2;
        for (int g16 = zwid; g16 < NGRP; g16 += ZW) {
            int s0 = offs[g16 << 4];
            int s1 = (g16 == NGRP - 1) ? Etot : offs[(g16 + 1) << 4];
            if (s1 != s0) continue;            // has entries -> gather flushes it
            int b = g16 >> 12;
            int cell0 = (g16 & 4095) << 4;
            float* ob = out + (size_t)b * Cc * BEV_HW + cell0;
            float4 z = make_float4(0.f, 0.f, 0.f, 0.f);
            #pragma unroll
            for (int it = 0; it < 8; it++)
                *(float4*)(ob + (size_t)(it * 16 + c0) * BEV_HW + (q << 2)) = z;
        }
        return;
    }

    // ---- gather-role: static entry range ----
    int wid  = blockIdx.x * 4 + w;
    int WCH  = (Etot + GW - 1) / GW;
    if (WCH <= 0) return;
    int start = wid * WCH;
    if (start >= Etot) return;
    int end = start + WCH; if (end > Etot) end = Etot;
    int k0 = 0;
    if (start > 0) {
        int segP = e8[start - 1].x >> 13;
        k0 = offs[segP] + cntArr[segP];          // end of segP's run
        if (k0 >= end) return;                   // no cell starts here
    }
    int segE = e8[end - 1].x >> 13;
    int kend = offs[segE] + cntArr[segE];        // extend thru straddler
    float* winw = win[w];

    int j = k0;
    while (j < kend) {
        int g16  = (e8[j].x >> 13) >> 4;         // group of this run (uniform)
        int gend = (g16 + 1) << 4;
        int jend = (gend < NSEG) ? offs[gend] : Etot;
        if (jend > kend) jend = kend;
        int tot = jend - j;

        float2 a = make_float2(0.f, 0.f);
        int curc = -1;
        unsigned mask = 0;

        int jj = 0;
        int2 e0, e1, e2, e3;
        if (tot >= 4) { e0 = e8[j]; e1 = e8[j+1]; e2 = e8[j+2]; e3 = e8[j+3]; }
        for (; jj + 8 <= tot; jj += 4) {
            float2 f0 = ft2[FIDX(e0)];
            float2 f1 = ft2[FIDX(e1)];
            float2 f2 = ft2[FIDX(e2)];
            float2 f3 = ft2[FIDX(e3)];
            int2 n0 = e8[j + jj + 4];
            int2 n1 = e8[j + jj + 5];
            int2 n2 = e8[j + jj + 6];
            int2 n3 = e8[j + jj + 7];
            G_STEP(e0, f0); G_STEP(e1, f1); G_STEP(e2, f2); G_STEP(e3, f3);
            e0 = n0; e1 = n1; e2 = n2; e3 = n3;
        }
        if (tot >= 4) {                          // drain the loaded batch
            float2 f0 = ft2[FIDX(e0)];
            float2 f1 = ft2[FIDX(e1)];
            float2 f2 = ft2[FIDX(e2)];
            float2 f3 = ft2[FIDX(e3)];
            G_STEP(e0, f0); G_STEP(e1, f1); G_STEP(e2, f2); G_STEP(e3, f3);
            jj += 4;
        }
        for (; jj < tot; jj++) {
            int2 ee = e8[j + jj];
            float2 f = ft2[FIDX(ee)];
            G_STEP(ee, f);
        }
        if (curc >= 0) {                         // close final cell of group
            *(float2*)&winw[(curc & 15) * 132 + 2 * lane] = a;
            mask |= 1u << (curc & 15);
        }

        // ---- flush group g16 (single site) ----
        int cntv = cntArr[(g16 << 4) + (lane & 15)];
        unsigned nz = (unsigned)__ballot(cntv > 0) & 0xFFFFu;
        unsigned wr = mask | (0xFFFFu & ~nz);    // mine or empty
        int b     = g16 >> 12;
        int cell0 = (g16 & 4095) << 4;
        float* ob = out + (size_t)b * Cc * BEV_HW + cell0;
        if (wr == 0xFFFFu) {
            int q = lane & 3, c0 = lane >> 2, g0 = q << 2;
            float n0 = (float)__shfl(cntv, g0);
            float n1 = (float)__shfl(cntv, g0 + 1);
            float n2 = (float)__shfl(cntv, g0 + 2);
            float n3 = (float)__shfl(cntv, g0 + 3);
            float i0 = __fdiv_rn(1.0f, __fadd_rn(n0, 1e-5f));
            float i1 = __fdiv_rn(1.0f, __fadd_rn(n1, 1e-5f));
            float i2 = __fdiv_rn(1.0f, __fadd_rn(n2, 1e-5f));
            float i3 = __fdiv_rn(1.0f, __fadd_rn(n3, 1e-5f));
            bool o0 = (mask >> (g0 + 0)) & 1u;
            bool o1 = (mask >> (g0 + 1)) & 1u;
            bool o2 = (mask >> (g0 + 2)) & 1u;
            bool o3 = (mask >> (g0 + 3)) & 1u;
            #pragma unroll
            for (int it = 0; it < 8; it++) {
                int c = it * 16 + c0;
                float4 v;
                v.x = o0 ? __fmul_rn(winw[(g0 + 0) * 132 + c], i0) : 0.f;
                v.y = o1 ? __fmul_rn(winw[(g0 + 1) * 132 + c], i1) : 0.f;
                v.z = o2 ? __fmul_rn(winw[(g0 + 2) * 132 + c], i2) : 0.f;
                v.w = o3 ? __fmul_rn(winw[(g0 + 3) * 132 + c], i3) : 0.f;
                *(float4*)(ob + (size_t)c * BEV_HW + g0) = v;
            }
        } else {
            int g = lane & 15, cq = lane >> 4;
            bool mine = (mask >> g) & 1u;
            bool wrb  = (wr >> g) & 1u;
            float inv = __fdiv_rn(1.0f, __fadd_rn((float)cntv, 1e-5f));
            #pragma unroll 4
            for (int c4 = 0; c4 < Cc; c4 += 4) {
                int c = c4 + cq;
                if (wrb) ob[(size_t)c * BEV_HW + g] =
                    mine ? __fmul_rn(winw[g * 132 + c], inv) : 0.f;
            }
        }
        j = jend;
    }
}

// ======================= fallback (round-2 proven) ==========================
__global__ __launch_bounds__(256) void k_classifyF(const float* __restrict__ Ki_all,
                                                   const float* __restrict__ db,
                                                   const float* __restrict__ extr,
                                                   int* __restrict__ idxT,
                                                   float* __restrict__ cnt) {
    int gid = blockIdx.x * 256 + threadIdx.x;
    if (gid >= NPTS) return;
    int cell = classify_point(gid, Ki_all, db, extr);
    idxT[gid] = cell;
    if (cell >= 0) {
        int b = gid / (Nc * Dc * HWc);
        atomicAdd(&cnt[b * BEV_HW + cell], 1.0f);
    }
}

__global__ __launch_bounds__(256) void k_scatterF(const float* __restrict__ feat,
                                                  const float* __restrict__ depth,
                                                  const int* __restrict__ idxT,
                                                  float* __restrict__ out) {
    __shared__ float s_dw[HWc];
    __shared__ int   s_idx[HWc];
    int blk = blockIdx.x;
    int bn  = blk / Dc;
    int b   = bn / Nc;
    int tid = threadIdx.x;
    const float* dp = depth + (size_t)blk * HWc;
    const int*   ip = idxT  + (size_t)blk * HWc;
    for (int p = tid; p < HWc; p += 256) { s_dw[p] = dp[p]; s_idx[p] = ip[p]; }
    __syncthreads();
    const float* fb = feat + (size_t)bn * Cc * HWc;
    float*       ob = out  + (size_t)b  * Cc * BEV_HW;
    for (int c = 0; c < Cc; c++) {
        const float* f = fb + (size_t)c * HWc;
        float*       o = ob + (size_t)c * BEV_HW;
        for (int p = tid; p < HWc; p += 256) {
            int cell = s_idx[p];
            if (cell >= 0) atomicAdd(&o[cell], __fmul_rn(f[p], s_dw[p]));
        }
    }
}

__global__ __launch_bounds__(256) void k_normF(float* __restrict__ out,
                                               const float* __restrict__ cnt) {
    int i = blockIdx.x * 256 + threadIdx.x;
    const int total = Bc * Cc * BEV_HW / 4;
    if (i >= total) return;
    int q = i % (BEV_HW / 4);
    int b = i / (Cc * BEV_HW / 4);
    float4 v = ((float4*)out)[i];
    float4 cv = ((const float4*)cnt)[b * (BEV_HW / 4) + q];
    v.x = __fdiv_rn(v.x, __fadd_rn(cv.x, 1e-5f));
    v.y = __fdiv_rn(v.y, __fadd_rn(cv.y, 1e-5f));
    v.z = __fdiv_rn(v.z, __fadd_rn(cv.z, 1e-5f));
    v.w = __fdiv_rn(v.w, __fadd_rn(cv.w, 1e-5f));
    ((float4*)out)[i] = v;
}

// ===========================================================================
extern "C" void kernel_launch(void* const* d_in, const int* in_sizes, int n_in,
                              void* d_out, int out_size, void* d_ws, size_t ws_size,
                              hipStream_t stream) {
    const float* feat  = (const float*)d_in[0];
    const float* depth = (const float*)d_in[1];
    const float* intr  = (const float*)d_in[2];
    const float* extr  = (const float*)d_in[3];
    const int*   imh   = (const int*)d_in[4];
    const int*   imw   = (const int*)d_in[5];
    float* out = (float*)d_out;
    char*  ws  = (char*)d_ws;

    if (ws_size >= (size_t)WS_BIG) {
        int*      cntA  = (int*)(ws + OFF_CNT);
        int*      offs  = (int*)(ws + OFF_OFFS);
        int*      bsum  = (int*)(ws + OFF_BSUM);
        int*      EtotG = (int*)(ws + OFF_ETOT);
        int2*     e8    = (int2*)(ws + OFF_E8);
        float*    ft    = (float*)(ws + OFF_FT);
        unsigned* pk    = (unsigned*)(ws + OFF_ACC);

        hipMemsetAsync(cntA, 0, (size_t)NSEG * sizeof(int), stream);
        k_count<<<NPTS / 256, 256, 0, stream>>>(intr, extr, imh, imw, feat, cntA, pk, ft);
        k_scanB<<<NSCANB, 256, 0, stream>>>(cntA, offs, bsum);
        k_scanT<<<NSCANB, 256, 0, stream>>>(offs, bsum, EtotG);
        k_fill<<<NPTS / 256, 256, 0, stream>>>(pk, depth, offs, e8);
        k_gatherW<<<GB + ZB, 256, 0, stream>>>((const float2*)ft, e8, cntA, offs, EtotG, out);
    } else {
        float* Ki   = (float*)(ws + OFF_KI);
        float* db   = (float*)(ws + OFF_DB);
        int*   idxT = (int*)(ws + OFF_FIDX);
        float* cnt  = (float*)(ws + OFF_FCNT);
        hipMemsetAsync(out, 0, (size_t)out_size * sizeof(float), stream);
        hipMemsetAsync(cnt, 0, (size_t)Bc * BEV_HW * sizeof(float), stream);
        k_setup<<<1, 64, 0, stream>>>(intr, extr, imh, imw, Ki, db);
        k_classifyF<<<(NPTS + 255) / 256, 256, 0, stream>>>(Ki, db, extr, idxT, cnt);
        k_scatterF<<<Bc * Nc * Dc, 256, 0, stream>>>(feat, depth, idxT, out);
        k_normF<<<(Bc * Cc * BEV_HW / 4 + 255) / 256, 256, 0, stream>>>(out, cnt);
    }
}